// Round 12
// baseline (185.493 us; speedup 1.0000x reference)
//
#include <hip/hip_runtime.h>
#include <hip/hip_bf16.h>
#include <hip/hip_fp16.h>
#include <cstdint>
#include <cstddef>

// Problem constants (fixed by reference setup_inputs)
#define EMBED  256
#define NV_PER_B 13294
#define M_PAD   26624          // 208 * 128
#define QCH    16              // queries per msda block (256 thr = 16q x 16 lanes, 1 head)

// Spatial pyramid (structural constants from reference SHAPES)
__constant__ const int c_H[4]  = {100, 50, 25, 13};
__constant__ const int c_W[4]  = {100, 50, 25, 13};
__constant__ const int c_ST[4] = {0, 10000, 12500, 13125};

typedef __attribute__((ext_vector_type(8))) short bf16x8;
typedef __attribute__((ext_vector_type(4))) float f32x4;

__device__ inline short f2bf(float x) {
    __hip_bfloat16 h = __float2bfloat16(x);
    return *reinterpret_cast<short*>(&h);
}

// fused f16*f16 + f32 accumulate: one VALU inst, exact f32 math
__device__ __forceinline__ void fmamix_lo(float& acc, unsigned w16, unsigned v2) {
    asm("v_fma_mix_f32 %0, %1, %2, %0 op_sel:[0,0,0] op_sel_hi:[1,1,0]"
        : "+v"(acc) : "v"(w16), "v"(v2));
}
__device__ __forceinline__ void fmamix_hi(float& acc, unsigned w16, unsigned v2) {
    asm("v_fma_mix_f32 %0, %1, %2, %0 op_sel:[0,1,0] op_sel_hi:[1,1,0]"
        : "+v"(acc) : "v"(w16), "v"(v2));
}

// ---------------- fp32 -> bf16 conversion + weight concat ----------------
__global__ __launch_bounds__(256) void convert_kernel(
    const float* __restrict__ q,  const float* __restrict__ v,
    const float* __restrict__ wv, const float* __restrict__ wsamp,
    const float* __restrict__ wattn, const float* __restrict__ wo,
    const float* __restrict__ bsamp, const float* __restrict__ battn,
    short* __restrict__ q_bf, short* __restrict__ v_bf,
    short* __restrict__ wv_bf, short* __restrict__ wcat_bf,
    short* __restrict__ wo_bf, float* __restrict__ bias_cat,
    int n_real4, int n_pad4)
{
    const int i = blockIdx.x * 256 + threadIdx.x;
    if (i < n_pad4) {
        float4 a = make_float4(0.f, 0.f, 0.f, 0.f);
        float4 b = make_float4(0.f, 0.f, 0.f, 0.f);
        if (i < n_real4) {
            a = ((const float4*)q)[i];
            b = ((const float4*)v)[i];
        }
        ((short4*)q_bf)[i] = make_short4(f2bf(a.x), f2bf(a.y), f2bf(a.z), f2bf(a.w));
        ((short4*)v_bf)[i] = make_short4(f2bf(b.x), f2bf(b.y), f2bf(b.z), f2bf(b.w));
    }
    if (i < 16384) {  // W_val, W_out: 65536/4 float4s each
        float4 a = ((const float4*)wv)[i];
        float4 c = ((const float4*)wo)[i];
        ((short4*)wv_bf)[i] = make_short4(f2bf(a.x), f2bf(a.y), f2bf(a.z), f2bf(a.w));
        ((short4*)wo_bf)[i] = make_short4(f2bf(c.x), f2bf(c.y), f2bf(c.z), f2bf(c.w));
    }
    if (i < 24576) {  // W_cat = [W_samp(256x256); W_attn(128x256)] -> 384x256
        float4 a = (i < 16384) ? ((const float4*)wsamp)[i]
                               : ((const float4*)wattn)[i - 16384];
        ((short4*)wcat_bf)[i] = make_short4(f2bf(a.x), f2bf(a.y), f2bf(a.z), f2bf(a.w));
    }
    if (i < 96) {     // bias_cat = [b_samp(256); b_attn(128)]
        float4 a = (i < 64) ? ((const float4*)bsamp)[i]
                            : ((const float4*)battn)[i - 64];
        ((float4*)bias_cat)[i] = a;
    }
}

// ---------------- shared GEMM K-loop (128x128 tile, K=256, bf16 MFMA) ----------------
// COUNTED-VMCNT PIPELINE (R9-verified): 3 LDS buffers x 16KB rotate;
// raw s_barrier + per-wave s_waitcnt vmcnt(4) -- never drain to 0 in the loop.
__device__ __forceinline__ void gemm_kloop(
    const short* __restrict__ A, const short* __restrict__ Wt,
    int bm, int bn, char* smem, f32x4 (&acc)[4][4],
    int t, int wave, int lane)
{
    constexpr int K = 256;
    const int row0 = t >> 2, row1 = row0 + 64;
    const int kbl  = t & 3;
    const int kbg0 = kbl ^ (row0 & 3);
    const int kbg1 = kbl ^ (row1 & 3);
    const size_t a0 = (size_t)(bm + row0) * K + kbg0 * 8;
    const size_t a1 = (size_t)(bm + row1) * K + kbg1 * 8;
    const size_t b0 = (size_t)(bn + row0) * K + kbg0 * 8;
    const size_t b1 = (size_t)(bn + row1) * K + kbg1 * 8;
    const int lr16 = lane & 15, qk = lane >> 4;
    const int swz  = (qk ^ (lr16 & 3)) * 16;
    const int wrow = wave & 1, wcol = wave >> 1;

    auto issue = [&](int buf, int k0) {
        char* sa = smem + buf * 16384 + wave * 1024;  // wave-uniform base
        char* sb = sa + 8192;
        __builtin_amdgcn_global_load_lds(
            (const __attribute__((address_space(1))) void*)(A + a0 + k0),
            (__attribute__((address_space(3))) void*)(sa), 16, 0, 0);
        __builtin_amdgcn_global_load_lds(
            (const __attribute__((address_space(1))) void*)(A + a1 + k0),
            (__attribute__((address_space(3))) void*)(sa + 4096), 16, 0, 0);
        __builtin_amdgcn_global_load_lds(
            (const __attribute__((address_space(1))) void*)(Wt + b0 + k0),
            (__attribute__((address_space(3))) void*)(sb), 16, 0, 0);
        __builtin_amdgcn_global_load_lds(
            (const __attribute__((address_space(1))) void*)(Wt + b1 + k0),
            (__attribute__((address_space(3))) void*)(sb + 4096), 16, 0, 0);
    };

    issue(0, 0);
    issue(1, 32);          // 8 loads in flight entering the loop
    #pragma unroll
    for (int it = 0; it < 8; ++it) {
        // wait for stage-it's 4 loads (newest 4 = next stage, still flying)
        if (it < 7) asm volatile("s_waitcnt vmcnt(4)" ::: "memory");
        else        asm volatile("s_waitcnt vmcnt(0)" ::: "memory");
        __builtin_amdgcn_sched_barrier(0);
        __builtin_amdgcn_s_barrier();          // raw barrier: no vmcnt drain
        __builtin_amdgcn_sched_barrier(0);
        if (it + 2 < 8) issue((it + 2) % 3, (it + 2) * 32);
        const char* sa = smem + (it % 3) * 16384;
        const char* sb = sa + 8192;
        bf16x8 af[4], bfr[4];
        #pragma unroll
        for (int mi = 0; mi < 4; ++mi)
            af[mi] = *(const bf16x8*)(sa + (wrow * 64 + mi * 16 + lr16) * 64 + swz);
        #pragma unroll
        for (int ni = 0; ni < 4; ++ni)
            bfr[ni] = *(const bf16x8*)(sb + (wcol * 64 + ni * 16 + lr16) * 64 + swz);
        #pragma unroll
        for (int mi = 0; mi < 4; ++mi)
            #pragma unroll
            for (int ni = 0; ni < 4; ++ni)
                acc[mi][ni] = __builtin_amdgcn_mfma_f32_16x16x32_bf16(
                    af[mi], bfr[ni], acc[mi][ni], 0, 0, 0);
    }
}

// ---------------- mega GEMM: value->vproj(fp16, HEAD-MAJOR) and query->qo(fp16) ----------------
__global__ __launch_bounds__(256) void gemm_mega_kernel(
    const short* __restrict__ v_bf, const short* __restrict__ wv_bf,
    const float* __restrict__ b_val, __half* __restrict__ vproj,
    const short* __restrict__ q_bf, const short* __restrict__ wcat_bf,
    const float* __restrict__ bias_cat, __half* __restrict__ qo)
{
    __shared__ __align__(16) char smem[49152];   // 3 x 16KB pipeline buffers
    const int t = threadIdx.x;
    const int wave = t >> 6, lane = t & 63;
    const int lr16 = lane & 15, qk = lane >> 4;
    const int wrow = wave & 1, wcol = wave >> 1;
    const int y = blockIdx.y;
    const int bm = blockIdx.x * 128;

    const short* A; const short* Wt; const float* bias; __half* Cc; int Nst, bn;
    if (y < 2) { A = v_bf; Wt = wv_bf;   bias = b_val;    Cc = vproj; Nst = 256; bn = y * 128; }
    else       { A = q_bf; Wt = wcat_bf; bias = bias_cat; Cc = qo;    Nst = 384; bn = (y - 2) * 128; }

    f32x4 acc[4][4] = {};
    gemm_kloop(A, Wt, bm, bn, smem, acc, t, wave, lane);

    // epilogue: per-wave LDS transpose (64x64 fp16, stride 72 halves = 144B) -> dwordx4 stores
    __syncthreads();   // full drain once; guards LDS reuse below
    __half* ep = (__half*)(smem + wave * 9216);
    const int colbase = bn + wcol * 64;
    float bv[4];
    #pragma unroll
    for (int ni = 0; ni < 4; ++ni) bv[ni] = bias[colbase + ni * 16 + lr16];
    #pragma unroll
    for (int mi = 0; mi < 4; ++mi)
        #pragma unroll
        for (int ni = 0; ni < 4; ++ni)
            #pragma unroll
            for (int r = 0; r < 4; ++r)
                ep[(mi * 16 + qk * 4 + r) * 72 + ni * 16 + lr16] =
                    __float2half(acc[mi][ni][r] + bv[ni]);
    __syncthreads();
    const int er = lane >> 3, ec = (lane & 7) * 8;
    #pragma unroll
    for (int pass = 0; pass < 8; ++pass) {
        const int r = pass * 8 + er;
        const int4 vv = *(const int4*)&ep[r * 72 + ec];
        const int grow = bm + wrow * 64 + r;
        if (y < 2) {
            // head-major vproj store; only real rows (pad rows never read by msda)
            if (grow < 2 * NV_PER_B) {
                const int bb  = (grow >= NV_PER_B) ? 1 : 0;
                const int ii  = grow - bb * NV_PER_B;
                const int col = colbase + ec;               // multiple of 8
                const size_t dst =
                    ((size_t)(bb * 8 + (col >> 5)) * NV_PER_B + ii) * 32 + (col & 31);
                *(int4*)&Cc[dst] = vv;                       // 16B aligned
            }
        } else {
            *(int4*)&Cc[(size_t)grow * Nst + colbase + ec] = vv;
        }
    }
}

// ---------------- final GEMM: core(bf16) @ W_out^T + b_out -> fp32 d_out ----------------
__global__ __launch_bounds__(256) void gemm_out_kernel(
    const short* __restrict__ corebf, const short* __restrict__ wo_bf,
    const float* __restrict__ b_out, float* __restrict__ C, int M)
{
    __shared__ __align__(16) char smem[49152];
    const int t = threadIdx.x;
    const int wave = t >> 6, lane = t & 63;
    const int lr16 = lane & 15, qk = lane >> 4;
    const int wrow = wave & 1, wcol = wave >> 1;
    const int bm = blockIdx.x * 128, bn = blockIdx.y * 128;

    f32x4 acc[4][4] = {};
    gemm_kloop(corebf, wo_bf, bm, bn, smem, acc, t, wave, lane);

    // epilogue: two half-passes of 32x64 f32 transpose (stride 68 f32 = 272B)
    const int colbase = bn + wcol * 64;
    float bv[4];
    #pragma unroll
    for (int ni = 0; ni < 4; ++ni) bv[ni] = b_out[colbase + ni * 16 + lr16];
    float* ep = (float*)(smem + wave * 8704);
    #pragma unroll
    for (int p = 0; p < 2; ++p) {
        __syncthreads();
        #pragma unroll
        for (int mh = 0; mh < 2; ++mh) {
            const int mi = p * 2 + mh;
            #pragma unroll
            for (int ni = 0; ni < 4; ++ni)
                #pragma unroll
                for (int r = 0; r < 4; ++r)
                    ep[(mh * 16 + qk * 4 + r) * 68 + ni * 16 + lr16] =
                        acc[mi][ni][r] + bv[ni];
        }
        __syncthreads();
        const int er = lane >> 4, ec = (lane & 15) * 4;
        #pragma unroll
        for (int j = 0; j < 8; ++j) {
            const int r = j * 4 + er;
            const float4 vv = *(const float4*)&ep[r * 68 + ec];
            const int grow = bm + wrow * 64 + p * 32 + r;
            if (grow < M)
                *(float4*)&C[(size_t)grow * 256 + colbase + ec] = vv;
        }
    }
}

// ---------------- MSDA sampling core ----------------
// Block = 16 queries x 16 lanes, ONE head per block; head = blockIdx.x & 7
// pins head h to XCD h (per-XCD gather set 1.7MB -> L2-resident).
// R12: HALF-BURST gather. Phase 2 in two halves of 4 tap-pairs: issue 8
// int4 gathers back-to-back, compute previous half's 64 fma_mix while they
// fly. ~8 loads in flight per wave (R10 had 1-2); peak regs ~90 (R11's
// 16-deep burst needed ~120+, suspected over the (256,4) 128-VGPR cap ->
// compile/launch failure).
__global__ __launch_bounds__(256, 4) void msda_core_kernel(
    const __half* __restrict__ vproj,   // (bs, 8, nv, 32) fp16 head-major
    const float* __restrict__ refp,     // (M, 8)
    const __half* __restrict__ qo,      // (M_PAD, 384): [0,256)=offsets, [256,384)=logits
    short* __restrict__ core,           // (M_PAD, 256) bf16
    int nq, int nv, int M)
{
    const int t = threadIdx.x;
    const int head  = blockIdx.x & 7;
    const int chunk = blockIdx.x >> 3;
    const int q  = t >> 4;              // 0..15
    const int gq = chunk * QCH + q;

    // [q][y][xh][lp]; lp padded to 18 -> rows 144B (16B-aligned)
    __shared__ __align__(16) uint2 s_tap[QCH][2][2][18];

    // ---- phase 1: one thread per (q,lp) computes 2y x 2xh taps ----
    {
        const int lp = t & 15, l = lp >> 2;
        const int gqc = min(gq, M - 1);
        const float logit = __half2float(qo[(size_t)gq * 384 + 256 + head * 16 + lp]);
        float m = logit;
        #pragma unroll
        for (int s = 1; s < 16; s <<= 1) m = fmaxf(m, __shfl_xor(m, s));
        const float ev = expf(logit - m);
        float ssum = ev;
        #pragma unroll
        for (int s = 1; s < 16; s <<= 1) ssum += __shfl_xor(ssum, s);
        const float aw = ev / ssum;

        const float2 off = __half22float2(
            *(const __half2*)&qo[(size_t)gq * 384 + (head * 16 + lp) * 2]);
        const float rx = refp[(size_t)gqc * 8 + l * 2];
        const float ry = refp[(size_t)gqc * 8 + l * 2 + 1];
        const int W = c_W[l], H = c_H[l], st = c_ST[l];
        const float fW = (float)W, fH = (float)H;
        const float lx = (rx + off.x / fW) * fW - 0.5f;
        const float ly = (ry + off.y / fH) * fH - 0.5f;
        const float x0f = floorf(lx), y0f = floorf(ly);
        const float fx = lx - x0f, fy = ly - y0f;
        const int x0 = (int)x0f, y0 = (int)y0f;
        const int x0c = min(max(x0, 0), W - 2);
        const float wx0 = (x0c == x0) ? (1.f - fx) : ((x0c == x0 + 1) ? fx : 0.f);
        const float wx1 = (x0c + 1 == x0) ? (1.f - fx) : ((x0c == x0) ? fx : 0.f);
        const int b = (gq >= nq) ? 1 : 0;
        const unsigned plane = (unsigned)((b * 8 + head) * nv);
        #pragma unroll
        for (int dy = 0; dy < 2; ++dy) {
            const int yv = y0 + dy;
            const bool okY = (yv >= 0) & (yv < H);
            const int yc = min(max(yv, 0), H - 1);
            const float wy = okY ? (dy ? fy : (1.f - fy)) * aw : 0.f;
            const unsigned boff = (plane + (unsigned)(st + yc * W + x0c)) << 6; // bytes
            s_tap[q][dy][0][lp] = make_uint2(
                boff, (unsigned)__half_as_ushort(__float2half(wy * wx0)));
            s_tap[q][dy][1][lp] = make_uint2(
                boff + 64u, (unsigned)__half_as_ushort(__float2half(wy * wx1)));
        }
    }
    __syncthreads();

    // ---- phase 2: two half-bursts (8 loads in flight) + fma_mix ----
    const int g   = t & 15;
    const int y   = g >> 3;
    const int xh  = (g >> 2) & 1;
    const int c8  = g & 3;
    const char* __restrict__ vbase = (const char*)vproj + c8 * 16;

    const uint2* taps = &s_tap[q][y][xh][0];
    float a[8] = {0.f, 0.f, 0.f, 0.f, 0.f, 0.f, 0.f, 0.f};

    // half A: pairs 0..3
    uint4 dA0 = *(const uint4*)&taps[0];
    uint4 dA1 = *(const uint4*)&taps[2];
    uint4 dA2 = *(const uint4*)&taps[4];
    uint4 dA3 = *(const uint4*)&taps[6];
    int4 vA0 = *(const int4*)(vbase + (size_t)dA0.x);
    int4 vA0b= *(const int4*)(vbase + (size_t)dA0.z);
    int4 vA1 = *(const int4*)(vbase + (size_t)dA1.x);
    int4 vA1b= *(const int4*)(vbase + (size_t)dA1.z);
    int4 vA2 = *(const int4*)(vbase + (size_t)dA2.x);
    int4 vA2b= *(const int4*)(vbase + (size_t)dA2.z);
    int4 vA3 = *(const int4*)(vbase + (size_t)dA3.x);
    int4 vA3b= *(const int4*)(vbase + (size_t)dA3.z);

    // half B: pairs 4..7 (issue while half A computes)
    uint4 dB0 = *(const uint4*)&taps[8];
    uint4 dB1 = *(const uint4*)&taps[10];
    uint4 dB2 = *(const uint4*)&taps[12];
    uint4 dB3 = *(const uint4*)&taps[14];
    int4 vB0 = *(const int4*)(vbase + (size_t)dB0.x);
    int4 vB0b= *(const int4*)(vbase + (size_t)dB0.z);
    int4 vB1 = *(const int4*)(vbase + (size_t)dB1.x);
    int4 vB1b= *(const int4*)(vbase + (size_t)dB1.z);
    int4 vB2 = *(const int4*)(vbase + (size_t)dB2.x);
    int4 vB2b= *(const int4*)(vbase + (size_t)dB2.z);
    int4 vB3 = *(const int4*)(vbase + (size_t)dB3.x);
    int4 vB3b= *(const int4*)(vbase + (size_t)dB3.z);

    auto fma16 = [&](unsigned w0, unsigned w1, const int4& r0, const int4& r1) {
        const unsigned* u0 = (const unsigned*)&r0;
        const unsigned* u1 = (const unsigned*)&r1;
        fmamix_lo(a[0], w0, u0[0]); fmamix_hi(a[1], w0, u0[0]);
        fmamix_lo(a[2], w0, u0[1]); fmamix_hi(a[3], w0, u0[1]);
        fmamix_lo(a[4], w0, u0[2]); fmamix_hi(a[5], w0, u0[2]);
        fmamix_lo(a[6], w0, u0[3]); fmamix_hi(a[7], w0, u0[3]);
        fmamix_lo(a[0], w1, u1[0]); fmamix_hi(a[1], w1, u1[0]);
        fmamix_lo(a[2], w1, u1[1]); fmamix_hi(a[3], w1, u1[1]);
        fmamix_lo(a[4], w1, u1[2]); fmamix_hi(a[5], w1, u1[2]);
        fmamix_lo(a[6], w1, u1[3]); fmamix_hi(a[7], w1, u1[3]);
    };
    fma16(dA0.y, dA0.w, vA0, vA0b);
    fma16(dA1.y, dA1.w, vA1, vA1b);
    fma16(dA2.y, dA2.w, vA2, vA2b);
    fma16(dA3.y, dA3.w, vA3, vA3b);
    fma16(dB0.y, dB0.w, vB0, vB0b);
    fma16(dB1.y, dB1.w, vB1, vB1b);
    fma16(dB2.y, dB2.w, vB2, vB2b);
    fma16(dB3.y, dB3.w, vB3, vB3b);

    #pragma unroll
    for (int i = 0; i < 8; ++i) a[i] += __shfl_xor(a[i], 4);
    #pragma unroll
    for (int i = 0; i < 8; ++i) a[i] += __shfl_xor(a[i], 8);

    if (((g & 12) == 0) && gq < M) {
        __align__(16) short o[8];
        #pragma unroll
        for (int i = 0; i < 8; ++i) o[i] = f2bf(a[i]);
        *(int4*)&core[(size_t)gq * 256 + head * 32 + c8 * 8] = *(const int4*)o;
    }
}

// ---------------- launch ----------------
extern "C" void kernel_launch(void* const* d_in, const int* in_sizes, int n_in,
                              void* d_out, int out_size, void* d_ws, size_t ws_size,
                              hipStream_t stream) {
    const float* query  = (const float*)d_in[0];
    const float* refp   = (const float*)d_in[1];
    const float* value  = (const float*)d_in[2];
    const float* W_samp = (const float*)d_in[6];
    const float* b_samp = (const float*)d_in[7];
    const float* W_attn = (const float*)d_in[8];
    const float* b_attn = (const float*)d_in[9];
    const float* W_val  = (const float*)d_in[10];
    const float* b_val  = (const float*)d_in[11];
    const float* W_out  = (const float*)d_in[12];
    const float* b_out  = (const float*)d_in[13];
    float* out = (float*)d_out;

    const int M  = in_sizes[0] / EMBED;   // 26588
    const int nq = NV_PER_B;
    const int nv = NV_PER_B;
    const int Mp = M_PAD;

    // workspace carve-up (~75.5 MB)
    char* p = (char*)d_ws;
    short*  q_bf   = (short*)p;  p += (size_t)Mp * 256 * 2;
    short*  v_bf   = (short*)p;  p += (size_t)Mp * 256 * 2;
    short*  corebf = (short*)p;  p += (size_t)Mp * 256 * 2;
    __half* vproj  = (__half*)p; p += (size_t)Mp * 256 * 2;
    __half* qo     = (__half*)p; p += (size_t)Mp * 384 * 2;
    short*  wv_bf  = (short*)p;  p += 65536 * 2;
    short*  wcat   = (short*)p;  p += 98304 * 2;
    short*  wo_bf  = (short*)p;  p += 65536 * 2;
    float*  biascat= (float*)p;  p += 384 * 4;

    const int n_real4 = M * 256 / 4;
    const int n_pad4  = Mp * 256 / 4;
    dim3 blk(256);

    convert_kernel<<<dim3((n_pad4 + 255) / 256), blk, 0, stream>>>(
        query, value, W_val, W_samp, W_attn, W_out, b_samp, b_attn,
        q_bf, v_bf, wv_bf, wcat, wo_bf, biascat, n_real4, n_pad4);

    const int mb = Mp / 128;  // 208
    gemm_mega_kernel<<<dim3(mb, 5), blk, 0, stream>>>(
        v_bf, wv_bf, b_val, vproj, q_bf, wcat, biascat, qo);

    const int nchunks = (M + QCH - 1) / QCH;   // 1662
    msda_core_kernel<<<dim3(8 * nchunks), blk, 0, stream>>>(
        vproj, refp, qo, corebf, nq, nv, M);

    gemm_out_kernel<<<dim3(mb, 2), blk, 0, stream>>>(
        corebf, wo_bf, b_out, out, M);
}